// Round 5
// baseline (385.265 us; speedup 1.0000x reference)
//
#include <hip/hip_runtime.h>
#include <hip/hip_bf16.h>

#define SEQ 2048
#define DIM 128
#define NBH 32
#define NROWS (NBH*SEQ)      // 65536
#define NBLK (NROWS/32)      // 2048
#define SCALE 0.08838834764831845f  // 1/sqrt(128)
#define QSC (0.08838834764831845f * 1.4426950408889634f)  // SCALE*log2(e): exp2(s') == exp(s*SCALE)

typedef __attribute__((ext_vector_type(8))) short short8;
typedef __attribute__((ext_vector_type(16))) float float16;

__device__ __forceinline__ unsigned short f2bf(float x) {
    union { float f; unsigned u; } v; v.f = x;
    unsigned r = v.u + 0x7fffu + ((v.u >> 16) & 1u);   // RNE
    return (unsigned short)(r >> 16);
}
__device__ __forceinline__ unsigned pack_bf16(float a, float b) {
    float2 f; f.x = a; f.y = b;
    __hip_bfloat162 h = __float22bfloat162_rn(f);
    union { __hip_bfloat162 h2; unsigned u; } cv; cv.h2 = h; return cv.u;
}
__device__ __forceinline__ void gl_lds16(const void* g, void* l) {
    __builtin_amdgcn_global_load_lds((const __attribute__((address_space(1))) unsigned int*)g,
                                     (__attribute__((address_space(3))) unsigned int*)l, 16, 0, 0);
}

// ---------------- LSH hash: PERM[code] == code ^ (code>>1)
__global__ void hash_kernel(const float* __restrict__ qg, const float* __restrict__ kg,
                            const float* __restrict__ proj,
                            int* __restrict__ qh, int* __restrict__ kh)
{
    int gw   = (int)((blockIdx.x * blockDim.x + threadIdx.x) >> 6);
    int lane = threadIdx.x & 63;
    const float* src; int* dst; int row;
    if (gw < NROWS) { src = qg; dst = qh; row = gw; }
    else            { src = kg; dst = kh; row = gw - NROWS; }
    const float* x = src + (size_t)row * DIM;
    float a0=0.f,a1=0.f,a2=0.f,a3=0.f,a4=0.f,a5=0.f,a6=0.f;
    #pragma unroll
    for (int h = 0; h < 2; ++h) {
        int d = lane + 64*h;
        float xv = x[d];
        const float* p = proj + d*7;
        a0 = fmaf(xv, p[0], a0); a1 = fmaf(xv, p[1], a1);
        a2 = fmaf(xv, p[2], a2); a3 = fmaf(xv, p[3], a3);
        a4 = fmaf(xv, p[4], a4); a5 = fmaf(xv, p[5], a5);
        a6 = fmaf(xv, p[6], a6);
    }
    #pragma unroll
    for (int off = 32; off > 0; off >>= 1) {
        a0 += __shfl_xor(a0, off, 64); a1 += __shfl_xor(a1, off, 64);
        a2 += __shfl_xor(a2, off, 64); a3 += __shfl_xor(a3, off, 64);
        a4 += __shfl_xor(a4, off, 64); a5 += __shfl_xor(a5, off, 64);
        a6 += __shfl_xor(a6, off, 64);
    }
    if (lane == 0) {
        int code = 0;
        if (a0 > 0.f) code |= 1;  if (a1 > 0.f) code |= 2;
        if (a2 > 0.f) code |= 4;  if (a3 > 0.f) code |= 8;
        if (a4 > 0.f) code |= 16; if (a5 > 0.f) code |= 32;
        if (a6 > 0.f) code |= 64;
        dst[row] = code ^ (code >> 1);
    }
}

// ---------------- parallel stable counting sort per (b,h)
__global__ __launch_bounds__(256) void sort_kernel(const int* __restrict__ qh,
                                                   int* __restrict__ sidx, int* __restrict__ qhs)
{
    __shared__ unsigned short cnt[128][257];
    __shared__ int startv[128];
    const int bh = blockIdx.x;
    const int t  = threadIdx.x;
    const int base = bh*SEQ;

    for (int i = t; i < 128*257; i += 256) ((unsigned short*)cnt)[i] = 0;
    __syncthreads();

    int hv[8];
    {
        int4 a = *(const int4*)(qh + base + t*8);
        int4 b = *(const int4*)(qh + base + t*8 + 4);
        hv[0]=a.x; hv[1]=a.y; hv[2]=a.z; hv[3]=a.w;
        hv[4]=b.x; hv[5]=b.y; hv[6]=b.z; hv[7]=b.w;
    }
    #pragma unroll
    for (int i = 0; i < 8; ++i) cnt[hv[i]][t]++;
    __syncthreads();

    if (t < 128) {
        unsigned s = 0;
        for (int j = 0; j < 256; ++j) { unsigned c = cnt[t][j]; cnt[t][j] = (unsigned short)s; s += c; }
        cnt[t][256] = (unsigned short)s;
    }
    __syncthreads();
    if (t == 0) {
        int s = 0;
        for (int v = 0; v < 128; ++v) { startv[v] = s; s += cnt[v][256]; }
    }
    __syncthreads();

    #pragma unroll
    for (int i = 0; i < 8; ++i) {
        const int v = hv[i];
        int prior = 0;
        #pragma unroll
        for (int j = 0; j < 8; ++j) if (j < i && hv[j] == v) ++prior;
        const int rank = startv[v] + (int)cnt[v][t] + prior;
        sidx[base + rank] = t*8 + i;
        qhs[base + rank]  = v;
    }
}

// ---------------- per-32-block criticality -> keep flag
__global__ void crit_kernel(const int* __restrict__ kh, const int* __restrict__ qhs,
                            float* __restrict__ keepg)
{
    int nb = blockIdx.x * blockDim.x + threadIdx.x;
    if (nb >= NBLK) return;
    int c = 0;
    #pragma unroll
    for (int i = 0; i < 32; ++i) c += (kh[nb*32+i] == qhs[nb*32+i]) ? 1 : 0;
    keepg[nb] = (c == 0) ? 1.0f : 0.0f;
}

// ---------------- prep: K -> bf16 row-major; V -> bf16 transposed [h][d][key]
__global__ __launch_bounds__(256) void prep_kernel(const float* __restrict__ kg,
                                                   const float* __restrict__ vg,
                                                   unsigned short* __restrict__ kbf,
                                                   unsigned short* __restrict__ vtg)
{
    __shared__ unsigned short T[128][72];
    const int t  = threadIdx.x;
    const int h  = blockIdx.x >> 5;
    const int sl = blockIdx.x & 31;
    const size_t base = ((size_t)h*SEQ + sl*64) * DIM;

    #pragma unroll
    for (int i = 0; i < 8; ++i) {
        const float4 f = *(const float4*)(kg + base + ((size_t)i*256 + t)*4);
        uint2 pk; pk.x = pack_bf16(f.x, f.y); pk.y = pack_bf16(f.z, f.w);
        *(uint2*)(kbf + base + ((size_t)i*256 + t)*4) = pk;
    }

    const int kk = t & 63, seg = t >> 6;
    #pragma unroll
    for (int i = 0; i < 8; ++i) {
        float4 f = *(const float4*)(vg + base + (size_t)kk*DIM + seg*32 + i*4);
        T[seg*32 + i*4 + 0][kk] = f2bf(f.x);
        T[seg*32 + i*4 + 1][kk] = f2bf(f.y);
        T[seg*32 + i*4 + 2][kk] = f2bf(f.z);
        T[seg*32 + i*4 + 3][kk] = f2bf(f.w);
    }
    __syncthreads();
    const int r = t >> 1, hf = t & 1;
    unsigned short* dst = vtg + ((size_t)h*DIM + r)*SEQ + sl*64 + hf*32;
    #pragma unroll
    for (int i = 0; i < 4; ++i)
        *(short8*)(dst + i*8) = *(const short8*)&T[r][hf*32 + i*8];
}

// ---------------- dense flash attention: bf16 MFMA, 64 q per wave (2 MFMA columns),
// 256 q per block, grid 256 (1 block/CU), double-buffered 64-key tiles, XOR-swizzled LDS.
// Halves per-CU LDS frag traffic vs 32q/wave; K/V frag reads feed 2 MFMAs each;
// two independent accumulator chains per wave give intra-wave ILP.
__global__ __launch_bounds__(256, 1) void dense_attn_mfma(
    const unsigned short* __restrict__ kbf, const unsigned short* __restrict__ vtg,
    const float* __restrict__ qg, float* __restrict__ outg)
{
    __shared__ __align__(16) unsigned short Kb[2][64*128];
    __shared__ __align__(16) unsigned short Vb[2][128*64];

    const int t    = threadIdx.x;
    const int lane = t & 63;
    const int w    = t >> 6;          // 4 waves
    const int q5   = lane >> 5;
    const int l31  = lane & 31;

    const int b    = blockIdx.x;      // 256 blocks
    const int head = b & 31;          // head h -> XCD h&7: all 8 q-blocks of a head share an XCD
    const int qblk = b >> 3 >> 2;     // == b >> 5, kept simple
    const int qb   = b >> 5;

    const float* Qg = qg + ((size_t)head*SEQ + qb*256 + w*64) * DIM;
    const unsigned short* Kh = kbf + (size_t)head*SEQ*DIM;
    const unsigned short* Vh = vtg + (size_t)head*DIM*SEQ;
    (void)qblk;

    union FR { unsigned u[4]; short8 s; };
    // Q frags, 2 columns of 32 q each: col c covers q = w*64 + c*32 + l31
    short8 Qf[2][8];
    #pragma unroll
    for (int c = 0; c < 2; ++c)
        #pragma unroll
        for (int ch = 0; ch < 8; ++ch) {
            const float* p = Qg + (size_t)(c*32 + l31)*DIM + ch*16 + q5*8;
            float4 f0 = *(const float4*)p;
            float4 f1 = *(const float4*)(p + 4);
            FR fr;
            fr.u[0] = pack_bf16(f0.x*QSC, f0.y*QSC);
            fr.u[1] = pack_bf16(f0.z*QSC, f0.w*QSC);
            fr.u[2] = pack_bf16(f1.x*QSC, f1.y*QSC);
            fr.u[3] = pack_bf16(f1.z*QSC, f1.w*QSC);
            Qf[c][ch] = fr.s;
        }

    float16 o[2][4];
    #pragma unroll
    for (int c = 0; c < 2; ++c)
        #pragma unroll
        for (int mt = 0; mt < 4; ++mt)
            #pragma unroll
            for (int r = 0; r < 16; ++r) o[c][mt][r] = 0.f;
    float lsum0 = 0.f, lsum1 = 0.f;

    auto stage = [&](int buf, int kt) {
        #pragma unroll
        for (int i = 0; i < 4; ++i) {
            const int j = w*4 + i;                 // j 0..15: 4 K rows each
            const int r = j*4 + (lane >> 4);
            const int u = (lane & 15) ^ (r & 7);
            gl_lds16(Kh + ((size_t)(kt*64 + r))*DIM + u*8, &Kb[buf][j*512]);
        }
        #pragma unroll
        for (int i = 0; i < 4; ++i) {
            const int j = w*4 + i;                 // j 0..15: 8 V^T rows each
            const int d = j*8 + (lane >> 3);
            const int u = (lane & 7) ^ (d & 7);
            gl_lds16(Vh + (size_t)d*SEQ + kt*64 + u*8, &Vb[buf][j*512]);
        }
    };

    stage(0, 0);

    for (int kt = 0; kt < SEQ/64; ++kt) {
        __syncthreads();
        if (kt + 1 < SEQ/64) stage((kt+1)&1, kt+1);
        const unsigned short* Kc = &Kb[kt&1][0];
        const unsigned short* Vc = &Vb[kt&1][0];

        #pragma unroll
        for (int s = 0; s < 2; ++s) {
            // S^T = K·Q^T for both q-columns; one K frag read feeds 2 MFMAs
            float16 sv0, sv1;
            #pragma unroll
            for (int r = 0; r < 16; ++r) { sv0[r] = 0.f; sv1[r] = 0.f; }
            #pragma unroll
            for (int ch = 0; ch < 8; ++ch) {
                const int r = s*32 + l31;
                const int p = (2*ch + q5) ^ (l31 & 7);
                short8 kf = *(const short8*)&Kc[r*128 + p*8];
                sv0 = __builtin_amdgcn_mfma_f32_32x32x16_bf16(kf, Qf[0][ch], sv0, 0, 0, 0);
                sv1 = __builtin_amdgcn_mfma_f32_32x32x16_bf16(kf, Qf[1][ch], sv1, 0, 0, 0);
            }
            // max-free softmax + pack, per column
            unsigned pk0[8], pk1[8];
            #pragma unroll
            for (int rp = 0; rp < 8; ++rp) {
                float a0 = exp2f(sv0[2*rp]);
                float a1 = exp2f(sv0[2*rp+1]);
                lsum0 += a0 + a1;
                pk0[rp] = pack_bf16(a0, a1);
                float b0 = exp2f(sv1[2*rp]);
                float b1 = exp2f(sv1[2*rp+1]);
                lsum1 += b0 + b1;
                pk1[rp] = pack_bf16(b0, b1);
            }
            // P^T -> B-operand frags via packed half-wave exchanges, per column
            FR f00, f01, f10, f11;
            {
                unsigned e0 = __shfl_xor(q5 ? pk0[0] : pk0[2], 32, 64);
                unsigned e1 = __shfl_xor(q5 ? pk0[1] : pk0[3], 32, 64);
                unsigned e2 = __shfl_xor(q5 ? pk0[4] : pk0[6], 32, 64);
                unsigned e3 = __shfl_xor(q5 ? pk0[5] : pk0[7], 32, 64);
                if (q5 == 0) {
                    f00.u[0]=pk0[0]; f00.u[1]=pk0[1]; f00.u[2]=e0;     f00.u[3]=e1;
                    f01.u[0]=pk0[4]; f01.u[1]=pk0[5]; f01.u[2]=e2;     f01.u[3]=e3;
                } else {
                    f00.u[0]=e0;     f00.u[1]=e1;     f00.u[2]=pk0[2]; f00.u[3]=pk0[3];
                    f01.u[0]=e2;     f01.u[1]=e3;     f01.u[2]=pk0[6]; f01.u[3]=pk0[7];
                }
            }
            {
                unsigned e0 = __shfl_xor(q5 ? pk1[0] : pk1[2], 32, 64);
                unsigned e1 = __shfl_xor(q5 ? pk1[1] : pk1[3], 32, 64);
                unsigned e2 = __shfl_xor(q5 ? pk1[4] : pk1[6], 32, 64);
                unsigned e3 = __shfl_xor(q5 ? pk1[5] : pk1[7], 32, 64);
                if (q5 == 0) {
                    f10.u[0]=pk1[0]; f10.u[1]=pk1[1]; f10.u[2]=e0;     f10.u[3]=e1;
                    f11.u[0]=pk1[4]; f11.u[1]=pk1[5]; f11.u[2]=e2;     f11.u[3]=e3;
                } else {
                    f10.u[0]=e0;     f10.u[1]=e1;     f10.u[2]=pk1[2]; f10.u[3]=pk1[3];
                    f11.u[0]=e2;     f11.u[1]=e3;     f11.u[2]=pk1[6]; f11.u[3]=pk1[7];
                }
            }
            // O^T += V^T·P^T; one V frag read feeds 2 MFMAs
            #pragma unroll
            for (int c = 0; c < 2; ++c) {
                short8 pf0 = c ? f01.s : f00.s;
                short8 pf1 = c ? f11.s : f10.s;
                #pragma unroll
                for (int mt = 0; mt < 4; ++mt) {
                    const int d = mt*32 + l31;
                    const int u = s*4 + c*2 + q5;
                    const int p2 = u ^ (l31 & 7);
                    short8 vf = *(const short8*)&Vc[d*64 + p2*8];
                    o[0][mt] = __builtin_amdgcn_mfma_f32_32x32x16_bf16(vf, pf0, o[0][mt], 0, 0, 0);
                    o[1][mt] = __builtin_amdgcn_mfma_f32_32x32x16_bf16(vf, pf1, o[1][mt], 0, 0, 0);
                }
            }
        }
    }

    #pragma unroll
    for (int c = 0; c < 2; ++c) {
        float ls = c ? lsum1 : lsum0;
        const float l = ls + __shfl_xor(ls, 32, 64);
        const float inv = 1.f / l;
        float* orow = outg + ((size_t)head*SEQ + qb*256 + w*64 + c*32 + l31) * DIM;
        #pragma unroll
        for (int mt = 0; mt < 4; ++mt)
            #pragma unroll
            for (int rg = 0; rg < 4; ++rg) {
                const int d0 = mt*32 + rg*8 + q5*4;
                float4 ov;
                ov.x = o[c][mt][rg*4+0]*inv; ov.y = o[c][mt][rg*4+1]*inv;
                ov.z = o[c][mt][rg*4+2]*inv; ov.w = o[c][mt][rg*4+3]*inv;
                *(float4*)(orow + d0) = ov;
            }
    }
}

// ---------------- blocked critical attention + MSE loss
__global__ __launch_bounds__(256) void crit_attn(
    const float* __restrict__ qg, const float* __restrict__ kg, const float* __restrict__ vg,
    const int* __restrict__ sidx, const float* __restrict__ keepg,
    const float* __restrict__ outg, float* __restrict__ lossp)
{
    __shared__ float Qs[32][132];
    __shared__ float Ks2[32][132];
    __shared__ float Vs[32][132];
    __shared__ float Sc[32][33];
    __shared__ float wsum[4];

    const int t  = threadIdx.x;
    const int nb = blockIdx.x;
    const int bh = nb >> 6;
    const int s0 = (nb & 63) * 32;
    const float kp = keepg[nb];
    const float* Qbase = qg + (size_t)bh*SEQ*DIM;
    const size_t rowbase = (size_t)nb * 32 * DIM;

    for (int i = t; i < 32*32; i += 256) {
        int row = i >> 5, c4 = (i & 31)*4;
        int qsrc = sidx[bh*SEQ + s0 + row];
        *(float4*)&Qs[row][c4] = *(const float4*)(Qbase + (size_t)qsrc*DIM + c4);
        float4 kv = *(const float4*)(kg + rowbase + (size_t)row*DIM + c4);
        kv.x*=kp; kv.y*=kp; kv.z*=kp; kv.w*=kp;
        *(float4*)&Ks2[row][c4] = kv;
        *(float4*)&Vs[row][c4] = *(const float4*)(vg + rowbase + (size_t)row*DIM + c4);
    }
    __syncthreads();

    const int r = t >> 3, u = t & 7;
    {
        float s[4] = {0.f,0.f,0.f,0.f};
        for (int d = 0; d < DIM; d += 4) {
            float4 a = *(const float4*)&Qs[r][d];
            #pragma unroll
            for (int j = 0; j < 4; ++j) {
                float4 bb = *(const float4*)&Ks2[u + 8*j][d];
                s[j]=fmaf(a.x,bb.x,s[j]); s[j]=fmaf(a.y,bb.y,s[j]);
                s[j]=fmaf(a.z,bb.z,s[j]); s[j]=fmaf(a.w,bb.w,s[j]);
            }
        }
        #pragma unroll
        for (int j = 0; j < 4; ++j) Sc[r][u+8*j] = s[j]*SCALE;
    }
    __syncthreads();
    if (t < 32) {
        float mx = -1e30f;
        for (int j = 0; j < 32; ++j) mx = fmaxf(mx, Sc[t][j]);
        float ls = 0.f;
        for (int j = 0; j < 32; ++j) { float p = __expf(Sc[t][j]-mx); Sc[t][j] = p; ls += p; }
        float inv = 1.f/ls;
        for (int j = 0; j < 32; ++j) Sc[t][j] *= inv;
    }
    __syncthreads();

    float sq = 0.f;
    {
        float acc[4][4];
        #pragma unroll
        for (int a2 = 0; a2 < 4; ++a2)
            #pragma unroll
            for (int b2 = 0; b2 < 4; ++b2) acc[a2][b2] = 0.f;
        for (int kk = 0; kk < 32; ++kk) {
            float p = Sc[r][kk];
            #pragma unroll
            for (int kq = 0; kq < 4; ++kq) {
                float4 vv = *(const float4*)&Vs[kk][kq*32 + u*4];
                acc[kq][0]=fmaf(p,vv.x,acc[kq][0]); acc[kq][1]=fmaf(p,vv.y,acc[kq][1]);
                acc[kq][2]=fmaf(p,vv.z,acc[kq][2]); acc[kq][3]=fmaf(p,vv.w,acc[kq][3]);
            }
        }
        const float* orow = outg + rowbase + (size_t)r*DIM;
        #pragma unroll
        for (int kq = 0; kq < 4; ++kq) {
            float4 oa = *(const float4*)(orow + kq*32 + u*4);
            float d0=acc[kq][0]-oa.x, d1=acc[kq][1]-oa.y, d2=acc[kq][2]-oa.z, d3=acc[kq][3]-oa.w;
            sq += d0*d0 + d1*d1 + d2*d2 + d3*d3;
        }
    }
    #pragma unroll
    for (int off = 32; off > 0; off >>= 1) sq += __shfl_down(sq, off, 64);
    if ((t & 63) == 0) wsum[t>>6] = sq;
    __syncthreads();
    if (t == 0) atomicAdd(lossp, (wsum[0]+wsum[1]+wsum[2]+wsum[3]) * (1.0f/8388608.0f));
}

extern "C" void kernel_launch(void* const* d_in, const int* in_sizes, int n_in,
                              void* d_out, int out_size, void* d_ws, size_t ws_size,
                              hipStream_t stream)
{
    const float* q    = (const float*)d_in[0];
    const float* k    = (const float*)d_in[1];
    const float* v    = (const float*)d_in[2];
    const float* proj = (const float*)d_in[3];
    float* out   = (float*)d_out;
    float* lossp = out + (out_size - 1);

    int* qh   = (int*)d_ws;
    int* kh   = qh + NROWS;
    int* sidx = kh + NROWS;
    int* qhs  = sidx + NROWS;
    float* keepg = (float*)(qhs + NROWS);
    unsigned short* kbf = (unsigned short*)(keepg + NBLK);   // 16 MB
    unsigned short* vtg = kbf + (size_t)NROWS*DIM;           // 16 MB

    hipMemsetAsync(lossp, 0, sizeof(float), stream);
    prep_kernel<<<NBH*32, 256, 0, stream>>>(k, v, kbf, vtg);
    hash_kernel<<<(2*NROWS)/4, 256, 0, stream>>>(q, k, proj, qh, kh);
    sort_kernel<<<NBH, 256, 0, stream>>>(qh, sidx, qhs);
    crit_kernel<<<NBLK/256, 256, 0, stream>>>(kh, qhs, keepg);
    dense_attn_mfma<<<256, 256, 0, stream>>>(kbf, vtg, q, out);
    crit_attn<<<NBLK, 256, 0, stream>>>(q, k, v, sidx, keepg, out, lossp);
}

// Round 6
// 333.159 us; speedup vs baseline: 1.1564x; 1.1564x over previous
//
#include <hip/hip_runtime.h>
#include <hip/hip_bf16.h>

#define SEQ 2048
#define DIM 128
#define NBH 32
#define NROWS (NBH*SEQ)      // 65536
#define NBLK (NROWS/32)      // 2048
#define SCALE 0.08838834764831845f  // 1/sqrt(128)
#define QSC (0.08838834764831845f * 1.4426950408889634f)  // SCALE*log2(e): exp2(s') == exp(s*SCALE)

typedef __attribute__((ext_vector_type(8))) short short8;
typedef __attribute__((ext_vector_type(16))) float float16;

__device__ __forceinline__ unsigned short f2bf(float x) {
    union { float f; unsigned u; } v; v.f = x;
    unsigned r = v.u + 0x7fffu + ((v.u >> 16) & 1u);   // RNE
    return (unsigned short)(r >> 16);
}
__device__ __forceinline__ unsigned pack_bf16(float a, float b) {
    float2 f; f.x = a; f.y = b;
    __hip_bfloat162 h = __float22bfloat162_rn(f);
    union { __hip_bfloat162 h2; unsigned u; } cv; cv.h2 = h; return cv.u;
}
__device__ __forceinline__ void gl_lds16(const void* g, void* l) {
    __builtin_amdgcn_global_load_lds((const __attribute__((address_space(1))) unsigned int*)g,
                                     (__attribute__((address_space(3))) unsigned int*)l, 16, 0, 0);
}

// ---------------- LSH hash: PERM[code] == code ^ (code>>1)
__global__ void hash_kernel(const float* __restrict__ qg, const float* __restrict__ kg,
                            const float* __restrict__ proj,
                            int* __restrict__ qh, int* __restrict__ kh)
{
    int gw   = (int)((blockIdx.x * blockDim.x + threadIdx.x) >> 6);
    int lane = threadIdx.x & 63;
    const float* src; int* dst; int row;
    if (gw < NROWS) { src = qg; dst = qh; row = gw; }
    else            { src = kg; dst = kh; row = gw - NROWS; }
    const float* x = src + (size_t)row * DIM;
    float a0=0.f,a1=0.f,a2=0.f,a3=0.f,a4=0.f,a5=0.f,a6=0.f;
    #pragma unroll
    for (int h = 0; h < 2; ++h) {
        int d = lane + 64*h;
        float xv = x[d];
        const float* p = proj + d*7;
        a0 = fmaf(xv, p[0], a0); a1 = fmaf(xv, p[1], a1);
        a2 = fmaf(xv, p[2], a2); a3 = fmaf(xv, p[3], a3);
        a4 = fmaf(xv, p[4], a4); a5 = fmaf(xv, p[5], a5);
        a6 = fmaf(xv, p[6], a6);
    }
    #pragma unroll
    for (int off = 32; off > 0; off >>= 1) {
        a0 += __shfl_xor(a0, off, 64); a1 += __shfl_xor(a1, off, 64);
        a2 += __shfl_xor(a2, off, 64); a3 += __shfl_xor(a3, off, 64);
        a4 += __shfl_xor(a4, off, 64); a5 += __shfl_xor(a5, off, 64);
        a6 += __shfl_xor(a6, off, 64);
    }
    if (lane == 0) {
        int code = 0;
        if (a0 > 0.f) code |= 1;  if (a1 > 0.f) code |= 2;
        if (a2 > 0.f) code |= 4;  if (a3 > 0.f) code |= 8;
        if (a4 > 0.f) code |= 16; if (a5 > 0.f) code |= 32;
        if (a6 > 0.f) code |= 64;
        dst[row] = code ^ (code >> 1);
    }
}

// ---------------- parallel stable counting sort per (b,h)
__global__ __launch_bounds__(256) void sort_kernel(const int* __restrict__ qh,
                                                   int* __restrict__ sidx, int* __restrict__ qhs)
{
    __shared__ unsigned short cnt[128][257];
    __shared__ int startv[128];
    const int bh = blockIdx.x;
    const int t  = threadIdx.x;
    const int base = bh*SEQ;

    for (int i = t; i < 128*257; i += 256) ((unsigned short*)cnt)[i] = 0;
    __syncthreads();

    int hv[8];
    {
        int4 a = *(const int4*)(qh + base + t*8);
        int4 b = *(const int4*)(qh + base + t*8 + 4);
        hv[0]=a.x; hv[1]=a.y; hv[2]=a.z; hv[3]=a.w;
        hv[4]=b.x; hv[5]=b.y; hv[6]=b.z; hv[7]=b.w;
    }
    #pragma unroll
    for (int i = 0; i < 8; ++i) cnt[hv[i]][t]++;
    __syncthreads();

    if (t < 128) {
        unsigned s = 0;
        for (int j = 0; j < 256; ++j) { unsigned c = cnt[t][j]; cnt[t][j] = (unsigned short)s; s += c; }
        cnt[t][256] = (unsigned short)s;
    }
    __syncthreads();
    if (t == 0) {
        int s = 0;
        for (int v = 0; v < 128; ++v) { startv[v] = s; s += cnt[v][256]; }
    }
    __syncthreads();

    #pragma unroll
    for (int i = 0; i < 8; ++i) {
        const int v = hv[i];
        int prior = 0;
        #pragma unroll
        for (int j = 0; j < 8; ++j) if (j < i && hv[j] == v) ++prior;
        const int rank = startv[v] + (int)cnt[v][t] + prior;
        sidx[base + rank] = t*8 + i;
        qhs[base + rank]  = v;
    }
}

// ---------------- per-32-block criticality -> keep flag
__global__ void crit_kernel(const int* __restrict__ kh, const int* __restrict__ qhs,
                            float* __restrict__ keepg)
{
    int nb = blockIdx.x * blockDim.x + threadIdx.x;
    if (nb >= NBLK) return;
    int c = 0;
    #pragma unroll
    for (int i = 0; i < 32; ++i) c += (kh[nb*32+i] == qhs[nb*32+i]) ? 1 : 0;
    keepg[nb] = (c == 0) ? 1.0f : 0.0f;
}

// ---------------- prep: K -> bf16 row-major; V -> bf16 transposed [h][d][key]
__global__ __launch_bounds__(256) void prep_kernel(const float* __restrict__ kg,
                                                   const float* __restrict__ vg,
                                                   unsigned short* __restrict__ kbf,
                                                   unsigned short* __restrict__ vtg)
{
    __shared__ unsigned short T[128][72];
    const int t  = threadIdx.x;
    const int h  = blockIdx.x >> 5;
    const int sl = blockIdx.x & 31;
    const size_t base = ((size_t)h*SEQ + sl*64) * DIM;

    #pragma unroll
    for (int i = 0; i < 8; ++i) {
        const float4 f = *(const float4*)(kg + base + ((size_t)i*256 + t)*4);
        uint2 pk; pk.x = pack_bf16(f.x, f.y); pk.y = pack_bf16(f.z, f.w);
        *(uint2*)(kbf + base + ((size_t)i*256 + t)*4) = pk;
    }

    const int kk = t & 63, seg = t >> 6;
    #pragma unroll
    for (int i = 0; i < 8; ++i) {
        float4 f = *(const float4*)(vg + base + (size_t)kk*DIM + seg*32 + i*4);
        T[seg*32 + i*4 + 0][kk] = f2bf(f.x);
        T[seg*32 + i*4 + 1][kk] = f2bf(f.y);
        T[seg*32 + i*4 + 2][kk] = f2bf(f.z);
        T[seg*32 + i*4 + 3][kk] = f2bf(f.w);
    }
    __syncthreads();
    const int r = t >> 1, hf = t & 1;
    unsigned short* dst = vtg + ((size_t)h*DIM + r)*SEQ + sl*64 + hf*32;
    #pragma unroll
    for (int i = 0; i < 4; ++i)
        *(short8*)(dst + i*8) = *(const short8*)&T[r][hf*32 + i*8];
}

// ---------------- dense flash attention: bf16 MFMA, round-4 geometry (128 q/block,
// 4 waves x 32 q, grid 512 = 2 blocks/CU = 2 waves/SIMD for TLP), with ALL LDS read
// addresses hoisted out of the K-loop: koff[8]/voff[4] precomputed per-lane, buf/s/mt
// become compile-time immediates via manual 2x-unrolled double-buffer loop.
__global__ __launch_bounds__(256, 2) void dense_attn_mfma(
    const unsigned short* __restrict__ kbf, const unsigned short* __restrict__ vtg,
    const float* __restrict__ qg, float* __restrict__ outg)
{
    __shared__ __align__(16) unsigned short KbF[2*8192];   // [buf][key(64) x d(128)]
    __shared__ __align__(16) unsigned short VbF[2*8192];   // [buf][d(128) x key(64)]

    const int t    = threadIdx.x;
    const int lane = t & 63;
    const int w    = t >> 6;
    const int q5   = lane >> 5;
    const int l31  = lane & 31;
    const int e    = l31 & 7;

    const int b    = blockIdx.x;      // 512 blocks
    const int slot = b >> 3;
    const int head = (b & 7) * 4 + (slot >> 4);   // XCD swizzle
    const int qblk = slot & 15;

    const float* Qg = qg + ((size_t)head*SEQ + qblk*128 + w*32) * DIM;
    const unsigned short* Kh = kbf + (size_t)head*SEQ*DIM;
    const unsigned short* Vh = vtg + (size_t)head*DIM*SEQ;

    // ---- kt-invariant LDS read offsets (shorts), swizzle baked in
    int koff[8], voff[4];
    #pragma unroll
    for (int ch = 0; ch < 8; ++ch) koff[ch] = l31*128 + (((2*ch + q5) ^ e) * 8);
    #pragma unroll
    for (int u = 0; u < 4; ++u)    voff[u]  = l31*64  + ((((u>>1)*4 + (u&1)*2 + q5) ^ e) * 8);

    // ---- kt-invariant staging pointers (advance by const per tile)
    const unsigned short* kgp[4]; unsigned short* kls[4];
    const unsigned short* vgp[4]; unsigned short* vls[4];
    #pragma unroll
    for (int i = 0; i < 4; ++i) {
        const int j = w*4 + i;
        const int r = j*4 + (lane >> 4);
        const int u = (lane & 15) ^ (r & 7);
        kgp[i] = Kh + r*DIM + u*8;            // += 8192 per tile
        kls[i] = KbF + j*512;
        const int d = j*8 + (lane >> 3);
        const int u2 = (lane & 7) ^ (d & 7);
        vgp[i] = Vh + (size_t)d*SEQ + u2*8;   // += 64 per tile
        vls[i] = VbF + j*512;
    }

    // ---- Q frags (B-operand), pre-scaled by SCALE*log2e
    union FR { unsigned u[4]; short8 s; };
    short8 Qf[8];
    #pragma unroll
    for (int ch = 0; ch < 8; ++ch) {
        const float* p = Qg + (size_t)l31*DIM + ch*16 + q5*8;
        float4 f0 = *(const float4*)p;
        float4 f1 = *(const float4*)(p + 4);
        FR fr;
        fr.u[0] = pack_bf16(f0.x*QSC, f0.y*QSC);
        fr.u[1] = pack_bf16(f0.z*QSC, f0.w*QSC);
        fr.u[2] = pack_bf16(f1.x*QSC, f1.y*QSC);
        fr.u[3] = pack_bf16(f1.z*QSC, f1.w*QSC);
        Qf[ch] = fr.s;
    }

    float16 o[4];
    #pragma unroll
    for (int mt = 0; mt < 4; ++mt)
        #pragma unroll
        for (int r = 0; r < 16; ++r) o[mt][r] = 0.f;
    float lsum = 0.f;

    auto stage = [&](const int buf) {
        #pragma unroll
        for (int i = 0; i < 4; ++i) gl_lds16(kgp[i], kls[i] + buf*8192);
        #pragma unroll
        for (int i = 0; i < 4; ++i) gl_lds16(vgp[i], vls[i] + buf*8192);
        #pragma unroll
        for (int i = 0; i < 4; ++i) { kgp[i] += 8192; vgp[i] += 64; }
    };

    auto body = [&](const int buf) {
        #pragma unroll
        for (int s = 0; s < 2; ++s) {
            float16 sv;
            #pragma unroll
            for (int r = 0; r < 16; ++r) sv[r] = 0.f;
            #pragma unroll
            for (int ch = 0; ch < 8; ++ch) {
                short8 kf = *(const short8*)&KbF[buf*8192 + s*4096 + koff[ch]];
                sv = __builtin_amdgcn_mfma_f32_32x32x16_bf16(kf, Qf[ch], sv, 0, 0, 0);
            }
            unsigned pk[8];
            #pragma unroll
            for (int rp = 0; rp < 8; ++rp) {
                float p0 = __builtin_amdgcn_exp2f(sv[2*rp]);
                float p1 = __builtin_amdgcn_exp2f(sv[2*rp+1]);
                lsum += p0 + p1;
                pk[rp] = pack_bf16(p0, p1);
            }
            unsigned e0 = __shfl_xor(q5 ? pk[0] : pk[2], 32, 64);
            unsigned e1 = __shfl_xor(q5 ? pk[1] : pk[3], 32, 64);
            unsigned e2 = __shfl_xor(q5 ? pk[4] : pk[6], 32, 64);
            unsigned e3 = __shfl_xor(q5 ? pk[5] : pk[7], 32, 64);
            FR c0, c1;
            if (q5 == 0) {
                c0.u[0]=pk[0]; c0.u[1]=pk[1]; c0.u[2]=e0;    c0.u[3]=e1;
                c1.u[0]=pk[4]; c1.u[1]=pk[5]; c1.u[2]=e2;    c1.u[3]=e3;
            } else {
                c0.u[0]=e0;    c0.u[1]=e1;    c0.u[2]=pk[2]; c0.u[3]=pk[3];
                c1.u[0]=e2;    c1.u[1]=e3;    c1.u[2]=pk[6]; c1.u[3]=pk[7];
            }
            #pragma unroll
            for (int c = 0; c < 2; ++c) {
                short8 pf = c ? c1.s : c0.s;
                #pragma unroll
                for (int mt = 0; mt < 4; ++mt) {
                    short8 vf = *(const short8*)&VbF[buf*8192 + mt*2048 + voff[s*2 + c]];
                    o[mt] = __builtin_amdgcn_mfma_f32_32x32x16_bf16(vf, pf, o[mt], 0, 0, 0);
                }
            }
        }
    };

    stage(0);                               // tile 0 -> buf0
    for (int kt2 = 0; kt2 < 16; ++kt2) {
        __syncthreads();                    // buf0 ready (DMA drained by barrier)
        stage(1);                           // tile 2*kt2+1 -> buf1
        body(0);                            // consume tile 2*kt2
        __syncthreads();                    // buf1 ready; buf0 reads done
        if (kt2 < 15) stage(0);             // tile 2*kt2+2 -> buf0
        body(1);                            // consume tile 2*kt2+1
    }

    const float l = lsum + __shfl_xor(lsum, 32, 64);
    const float inv = 1.f / l;
    float* orow = outg + ((size_t)head*SEQ + qblk*128 + w*32 + l31) * DIM;
    #pragma unroll
    for (int mt = 0; mt < 4; ++mt)
        #pragma unroll
        for (int rg = 0; rg < 4; ++rg) {
            const int d0 = mt*32 + rg*8 + q5*4;
            float4 ov;
            ov.x = o[mt][rg*4+0]*inv; ov.y = o[mt][rg*4+1]*inv;
            ov.z = o[mt][rg*4+2]*inv; ov.w = o[mt][rg*4+3]*inv;
            *(float4*)(orow + d0) = ov;
        }
}

// ---------------- blocked critical attention + MSE loss
__global__ __launch_bounds__(256) void crit_attn(
    const float* __restrict__ qg, const float* __restrict__ kg, const float* __restrict__ vg,
    const int* __restrict__ sidx, const float* __restrict__ keepg,
    const float* __restrict__ outg, float* __restrict__ lossp)
{
    __shared__ float Qs[32][132];
    __shared__ float Ks2[32][132];
    __shared__ float Vs[32][132];
    __shared__ float Sc[32][33];
    __shared__ float wsum[4];

    const int t  = threadIdx.x;
    const int nb = blockIdx.x;
    const int bh = nb >> 6;
    const int s0 = (nb & 63) * 32;
    const float kp = keepg[nb];
    const float* Qbase = qg + (size_t)bh*SEQ*DIM;
    const size_t rowbase = (size_t)nb * 32 * DIM;

    for (int i = t; i < 32*32; i += 256) {
        int row = i >> 5, c4 = (i & 31)*4;
        int qsrc = sidx[bh*SEQ + s0 + row];
        *(float4*)&Qs[row][c4] = *(const float4*)(Qbase + (size_t)qsrc*DIM + c4);
        float4 kv = *(const float4*)(kg + rowbase + (size_t)row*DIM + c4);
        kv.x*=kp; kv.y*=kp; kv.z*=kp; kv.w*=kp;
        *(float4*)&Ks2[row][c4] = kv;
        *(float4*)&Vs[row][c4] = *(const float4*)(vg + rowbase + (size_t)row*DIM + c4);
    }
    __syncthreads();

    const int r = t >> 3, u = t & 7;
    {
        float s[4] = {0.f,0.f,0.f,0.f};
        for (int d = 0; d < DIM; d += 4) {
            float4 a = *(const float4*)&Qs[r][d];
            #pragma unroll
            for (int j = 0; j < 4; ++j) {
                float4 bb = *(const float4*)&Ks2[u + 8*j][d];
                s[j]=fmaf(a.x,bb.x,s[j]); s[j]=fmaf(a.y,bb.y,s[j]);
                s[j]=fmaf(a.z,bb.z,s[j]); s[j]=fmaf(a.w,bb.w,s[j]);
            }
        }
        #pragma unroll
        for (int j = 0; j < 4; ++j) Sc[r][u+8*j] = s[j]*SCALE;
    }
    __syncthreads();
    if (t < 32) {
        float mx = -1e30f;
        for (int j = 0; j < 32; ++j) mx = fmaxf(mx, Sc[t][j]);
        float ls = 0.f;
        for (int j = 0; j < 32; ++j) { float p = __expf(Sc[t][j]-mx); Sc[t][j] = p; ls += p; }
        float inv = 1.f/ls;
        for (int j = 0; j < 32; ++j) Sc[t][j] *= inv;
    }
    __syncthreads();

    float sq = 0.f;
    {
        float acc[4][4];
        #pragma unroll
        for (int a2 = 0; a2 < 4; ++a2)
            #pragma unroll
            for (int b2 = 0; b2 < 4; ++b2) acc[a2][b2] = 0.f;
        for (int kk = 0; kk < 32; ++kk) {
            float p = Sc[r][kk];
            #pragma unroll
            for (int kq = 0; kq < 4; ++kq) {
                float4 vv = *(const float4*)&Vs[kk][kq*32 + u*4];
                acc[kq][0]=fmaf(p,vv.x,acc[kq][0]); acc[kq][1]=fmaf(p,vv.y,acc[kq][1]);
                acc[kq][2]=fmaf(p,vv.z,acc[kq][2]); acc[kq][3]=fmaf(p,vv.w,acc[kq][3]);
            }
        }
        const float* orow = outg + rowbase + (size_t)r*DIM;
        #pragma unroll
        for (int kq = 0; kq < 4; ++kq) {
            float4 oa = *(const float4*)(orow + kq*32 + u*4);
            float d0=acc[kq][0]-oa.x, d1=acc[kq][1]-oa.y, d2=acc[kq][2]-oa.z, d3=acc[kq][3]-oa.w;
            sq += d0*d0 + d1*d1 + d2*d2 + d3*d3;
        }
    }
    #pragma unroll
    for (int off = 32; off > 0; off >>= 1) sq += __shfl_down(sq, off, 64);
    if ((t & 63) == 0) wsum[t>>6] = sq;
    __syncthreads();
    if (t == 0) atomicAdd(lossp, (wsum[0]+wsum[1]+wsum[2]+wsum[3]) * (1.0f/8388608.0f));
}

extern "C" void kernel_launch(void* const* d_in, const int* in_sizes, int n_in,
                              void* d_out, int out_size, void* d_ws, size_t ws_size,
                              hipStream_t stream)
{
    const float* q    = (const float*)d_in[0];
    const float* k    = (const float*)d_in[1];
    const float* v    = (const float*)d_in[2];
    const float* proj = (const float*)d_in[3];
    float* out   = (float*)d_out;
    float* lossp = out + (out_size - 1);

    int* qh   = (int*)d_ws;
    int* kh   = qh + NROWS;
    int* sidx = kh + NROWS;
    int* qhs  = sidx + NROWS;
    float* keepg = (float*)(qhs + NROWS);
    unsigned short* kbf = (unsigned short*)(keepg + NBLK);   // 16 MB
    unsigned short* vtg = kbf + (size_t)NROWS*DIM;           // 16 MB

    hipMemsetAsync(lossp, 0, sizeof(float), stream);
    prep_kernel<<<NBH*32, 256, 0, stream>>>(k, v, kbf, vtg);
    hash_kernel<<<(2*NROWS)/4, 256, 0, stream>>>(q, k, proj, qh, kh);
    sort_kernel<<<NBH, 256, 0, stream>>>(qh, sidx, qhs);
    crit_kernel<<<NBLK/256, 256, 0, stream>>>(kh, qhs, keepg);
    dense_attn_mfma<<<512, 256, 0, stream>>>(kbf, vtg, q, out);
    crit_attn<<<NBLK, 256, 0, stream>>>(q, k, v, sidx, keepg, out, lossp);
}